// Round 7
// baseline (397.135 us; speedup 1.0000x reference)
//
#include <hip/hip_runtime.h>
#include <hip/hip_bf16.h>

#define N_NODES 50000
#define IN_DIM 256
#define OUT_DIM 128
#define ODIM2 256        // mu(128) + logstd(128) concatenated
#define NEDGE 800000
#define MAX_LOGSTD 10.0f
#define NBLK 196         // ceil(50000/256)

typedef short bf16x8 __attribute__((ext_vector_type(8)));
typedef float f32x4  __attribute__((ext_vector_type(4)));

__device__ __forceinline__ float b2f(unsigned short u) {
    union { unsigned int i; float f; } v; v.i = ((unsigned int)u) << 16; return v.f;
}
__device__ __forceinline__ unsigned short f2b(float f) {
    union { float f; unsigned int i; } v; v.f = f;
    unsigned int x = v.i;
    unsigned int r = (x + 0x7fffu + ((x >> 16) & 1u)) >> 16;
    return (unsigned short)r;
}
__device__ __forceinline__ bool edges_are_i64(const int* raw) {
    bool is64 = true;
    #pragma unroll
    for (int i = 0; i < 8; i++) if (raw[2 * i + 1] != 0) is64 = false;
    return is64;
}

// dst histogram straight from raw edge buffer (int64 or int32 auto-detected)
__global__ void k_count(const int* __restrict__ raw, int* __restrict__ cnt) {
    bool is64 = edges_are_i64(raw);
    int e = blockIdx.x * blockDim.x + threadIdx.x;
    if (e < NEDGE) {
        int dst = is64 ? raw[2 * (NEDGE + e)] : raw[NEDGE + e];
        atomicAdd(&cnt[dst], 1);
    }
}

// Phase 1: per-block (256 counts) sums
__global__ __launch_bounds__(256) void k_blocksum(const int* __restrict__ cnt,
                                                  int* __restrict__ bsum) {
    int idx = blockIdx.x * 256 + threadIdx.x;
    int v = (idx < N_NODES) ? cnt[idx] : 0;
    #pragma unroll
    for (int o = 32; o > 0; o >>= 1) v += __shfl_down(v, o);
    __shared__ int wsum[4];
    int lane = threadIdx.x & 63, w = threadIdx.x >> 6;
    if (lane == 0) wsum[w] = v;
    __syncthreads();
    if (threadIdx.x == 0) bsum[blockIdx.x] = wsum[0] + wsum[1] + wsum[2] + wsum[3];
}

// Phase 2: scan 196 block sums -> exclusive block offsets
__global__ __launch_bounds__(256) void k_scanblocks(const int* __restrict__ bsum,
                                                    int* __restrict__ boff) {
    __shared__ int s[256];
    int t = threadIdx.x;
    s[t] = (t < NBLK) ? bsum[t] : 0;
    __syncthreads();
    for (int o = 1; o < 256; o <<= 1) {
        int v = (t >= o) ? s[t - o] : 0;
        __syncthreads();
        s[t] += v;
        __syncthreads();
    }
    if (t < NBLK) boff[t] = (t == 0) ? 0 : s[t - 1];
}

// Phase 3: in-block exclusive scan + offset -> row_start, pos; dinv fused.
__global__ __launch_bounds__(256) void k_apply(const int* __restrict__ cnt,
                                               const int* __restrict__ boff,
                                               int* __restrict__ row_start,
                                               int* __restrict__ pos,
                                               float* __restrict__ dinv) {
    __shared__ int s[256];
    int t = threadIdx.x;
    int idx = blockIdx.x * 256 + t;
    int c = (idx < N_NODES) ? cnt[idx] : 0;
    s[t] = c;
    __syncthreads();
    for (int o = 1; o < 256; o <<= 1) {
        int v = (t >= o) ? s[t - o] : 0;
        __syncthreads();
        s[t] += v;
        __syncthreads();
    }
    int excl = boff[blockIdx.x] + s[t] - c;
    if (idx < N_NODES) {
        row_start[idx] = excl;
        pos[idx] = excl;
        dinv[idx] = rsqrtf((float)c + 1.0f);
    }
    if (idx == N_NODES - 1) row_start[N_NODES] = NEDGE;
}

// Bin edges by dst directly from raw: csr[row_start[dst]+k] = src
__global__ void k_fill(const int* __restrict__ raw, int* __restrict__ pos,
                       int* __restrict__ csr) {
    bool is64 = edges_are_i64(raw);
    int e = blockIdx.x * blockDim.x + threadIdx.x;
    if (e < NEDGE) {
        int src = is64 ? raw[2 * e] : raw[e];
        int dst = is64 ? raw[2 * (NEDGE + e)] : raw[NEDGE + e];
        int p = atomicAdd(&pos[dst], 1);
        csr[p] = src;
    }
}

// Pack concat(Wmu,Wls) [256 x 256] f32 into B-fragment-ordered bf16:
// Wp[((tile*8 + kk)*64 + lane)*8 + j] = W[kk*32 + (lane>>4)*8 + j][tile*16 + (lane&15)]
__global__ void k_wconv(const float* __restrict__ Wmu, const float* __restrict__ Wls,
                        unsigned short* __restrict__ Wp) {
    int i = blockIdx.x * blockDim.x + threadIdx.x;   // 8192 threads
    int lane = i & 63;
    int kk   = (i >> 6) & 7;
    int tile = i >> 9;
    int k0 = kk * 32 + (lane >> 4) * 8;
    int n  = tile * 16 + (lane & 15);
    const float* W = (n < 128) ? (Wmu + n) : (Wls + (n - 128));
    unsigned short o[8];
    #pragma unroll
    for (int j = 0; j < 8; j++) o[j] = f2b(W[(size_t)(k0 + j) * OUT_DIM]);
    ushort4 lo = { o[0], o[1], o[2], o[3] };
    ushort4 hi = { o[4], o[5], o[6], o[7] };
    *(ushort4*)(Wp + (size_t)i * 8)     = lo;
    *(ushort4*)(Wp + (size_t)i * 8 + 4) = hi;
}

// MFMA GEMM -> h2 in SLICE-MAJOR layout:
// h2[((s*N + n)*32 + k], k<16: mu col 16s+k ; k>=16: logstd col 128+16s+(k-16).
// So each (node, slice) is one contiguous 64B segment = one edge-gather unit.
__global__ __launch_bounds__(256, 2) void k_gemm_mfma(
    const float* __restrict__ x, const unsigned short* __restrict__ Wp,
    unsigned short* __restrict__ h2)
{
    __shared__ unsigned short xs[64 * 256];   // 32 KB, swizzled
    const int tid  = threadIdx.x;
    const int lane = tid & 63;
    const int w    = tid >> 6;
    const int row0 = blockIdx.x * 64;

    // B fragments for this wave's 4 col-tiles, all 8 k-steps: loaded ONCE.
    bf16x8 breg[4][8];
    #pragma unroll
    for (int t = 0; t < 4; t++)
        #pragma unroll
        for (int kk = 0; kk < 8; kk++)
            breg[t][kk] = ((const bf16x8*)Wp)[((4 * w + t) * 8 + kk) * 64 + lane];

    // stage 64x256 f32 -> bf16 (XOR-swizzled rows)
    #pragma unroll
    for (int i = 0; i < 16; i++) {
        int f   = i * 256 + tid;
        int row = f >> 6;
        int c4  = f & 63;
        int grow = row0 + row;
        float4 v = make_float4(0.f, 0.f, 0.f, 0.f);
        if (grow < N_NODES) v = *(const float4*)(x + (size_t)grow * IN_DIM + c4 * 4);
        ushort4 b = { f2b(v.x), f2b(v.y), f2b(v.z), f2b(v.w) };
        unsigned int byte = (unsigned)(row * 512 + c4 * 8);
        byte ^= (unsigned)((row & 7) << 4);
        *(ushort4*)((char*)xs + byte) = b;
    }
    __syncthreads();

    #pragma unroll
    for (int sub = 0; sub < 4; sub++) {
        const int arow = sub * 16 + (lane & 15);
        const unsigned int abase = (unsigned)(arow * 512 + (lane >> 4) * 16);
        const unsigned int axor  = (unsigned)((arow & 7) << 4);

        bf16x8 a[8];
        #pragma unroll
        for (int kk = 0; kk < 8; kk++)
            a[kk] = *(const bf16x8*)((const char*)xs + ((abase + kk * 64) ^ axor));

        f32x4 acc[4];
        #pragma unroll
        for (int t = 0; t < 4; t++) acc[t] = (f32x4){0.f, 0.f, 0.f, 0.f};

        #pragma unroll
        for (int kk = 0; kk < 8; kk++)
            #pragma unroll
            for (int t = 0; t < 4; t++)
                acc[t] = __builtin_amdgcn_mfma_f32_16x16x32_bf16(a[kk], breg[t][kk],
                                                                 acc[t], 0, 0, 0);

        // C/D layout: col=lane&15, row=(lane>>4)*4+reg -> scatter into h2 slices
        const int rbase = row0 + sub * 16 + (lane >> 4) * 4;
        const int cl = lane & 15;
        #pragma unroll
        for (int t = 0; t < 4; t++) {
            int col  = (4 * w + t) * 16 + cl;
            int half = col >> 7;
            int cpos = col & 127;
            int s    = cpos >> 4;
            int k    = half * 16 + (cpos & 15);
            #pragma unroll
            for (int r = 0; r < 4; r++) {
                int row = rbase + r;
                if (row < N_NODES)
                    h2[((size_t)s * N_NODES + row) * 32 + k] = f2b(acc[t][r]);
            }
        }
    }
}

// Sliced gather: block handles slice s = blockIdx&7 for 4 nodes (1/wave).
// With round-robin block->XCD dispatch, XCD s only touches its 3.2MB h2 stripe
// -> edge gathers become L2 hits. 16-lane groups process 4 edges in parallel;
// lane j<8: mu pair, j>=8: ls pair. Butterfly-reduce groups, fused reparam.
// NOTE: self-loop seeded by subgroup g==0 ONLY (it survives the reduction once).
__global__ __launch_bounds__(256) void k_gather_s(
    const int* __restrict__ row_start, const int* __restrict__ csr,
    const float* __restrict__ dinv, const unsigned short* __restrict__ h2,
    const float* __restrict__ eps, const float* __restrict__ bmu,
    const float* __restrict__ bls, float* __restrict__ z)
{
    const int tid  = threadIdx.x;
    const int w    = tid >> 6;
    const int lane = tid & 63;
    const int s    = blockIdx.x & 7;
    const int n    = (blockIdx.x >> 3) * 4 + w;
    const int g    = lane >> 4;     // edge subgroup 0..3
    const int j    = lane & 15;     // column-pair index within slice

    const float dn = dinv[n];
    const unsigned short* hb = h2 + (size_t)s * ((size_t)N_NODES * 32);

    float a0 = 0.0f, a1 = 0.0f;
    if (g == 0) {   // self-loop: dinv^2 * h[n]  (exactly once across subgroups)
        ushort2 v = *(const ushort2*)(hb + (size_t)n * 32 + 2 * j);
        float c = dn * dn;
        a0 = c * b2f(v.x);
        a1 = c * b2f(v.y);
    }

    const int beg = row_start[n];
    const int end = row_start[n + 1];
    int e = beg + g;
    // 2-deep unroll for MLP (each group strides by 4)
    for (; e + 4 < end; e += 8) {
        int s0 = __builtin_nontemporal_load(&csr[e]);
        int s1 = __builtin_nontemporal_load(&csr[e + 4]);
        float c0 = dinv[s0] * dn;
        float c1 = dinv[s1] * dn;
        ushort2 v0 = *(const ushort2*)(hb + (size_t)s0 * 32 + 2 * j);
        ushort2 v1 = *(const ushort2*)(hb + (size_t)s1 * 32 + 2 * j);
        a0 = fmaf(c0, b2f(v0.x), a0);
        a1 = fmaf(c0, b2f(v0.y), a1);
        a0 = fmaf(c1, b2f(v1.x), a0);
        a1 = fmaf(c1, b2f(v1.y), a1);
    }
    if (e < end) {
        int s0 = __builtin_nontemporal_load(&csr[e]);
        float c0 = dinv[s0] * dn;
        ushort2 v0 = *(const ushort2*)(hb + (size_t)s0 * 32 + 2 * j);
        a0 = fmaf(c0, b2f(v0.x), a0);
        a1 = fmaf(c0, b2f(v0.y), a1);
    }

    // reduce the 4 edge subgroups (same j) -> every lane holds the full sum
    a0 += __shfl_xor(a0, 16); a0 += __shfl_xor(a0, 32);
    a1 += __shfl_xor(a1, 16); a1 += __shfl_xor(a1, 32);

    // logstd pairs live on lanes j>=8 of the same group
    float l0 = __shfl(a0, lane + 8);
    float l1 = __shfl(a1, lane + 8);

    if (lane < 8) {
        int c0 = s * 16 + 2 * j;     // output column pair
        float ep0 = __builtin_nontemporal_load(&eps[(size_t)n * OUT_DIM + c0]);
        float ep1 = __builtin_nontemporal_load(&eps[(size_t)n * OUT_DIM + c0 + 1]);
        float z0 = a0 + bmu[c0]     + ep0 * expf(fminf(l0 + bls[c0],     MAX_LOGSTD));
        float z1 = a1 + bmu[c0 + 1] + ep1 * expf(fminf(l1 + bls[c0 + 1], MAX_LOGSTD));
        __builtin_nontemporal_store(z0, &z[(size_t)n * OUT_DIM + c0]);
        __builtin_nontemporal_store(z1, &z[(size_t)n * OUT_DIM + c0 + 1]);
    }
}

extern "C" void kernel_launch(void* const* d_in, const int* in_sizes, int n_in,
                              void* d_out, int out_size, void* d_ws, size_t ws_size,
                              hipStream_t stream) {
    const float* x   = (const float*)d_in[0];
    const int*   ei  = (const int*)  d_in[1];
    const float* Wmu = (const float*)d_in[2];
    const float* bmu = (const float*)d_in[3];
    const float* Wls = (const float*)d_in[4];
    const float* bls = (const float*)d_in[5];
    const float* eps = (const float*)d_in[6];
    float* z = (float*)d_out;

    char* ws = (char*)d_ws;
    size_t off = 0;
    auto alloc = [&](size_t bytes) {
        void* p = ws + off;
        off += (bytes + 255) & ~(size_t)255;
        return p;
    };
    int*   cnt       = (int*)  alloc((size_t)N_NODES * 4);
    float* dinv      = (float*)alloc((size_t)N_NODES * 4);
    int*   row_start = (int*)  alloc((size_t)(N_NODES + 1) * 4);
    int*   pos       = (int*)  alloc((size_t)N_NODES * 4);
    int*   csr       = (int*)  alloc((size_t)NEDGE * 4);
    int*   bsum      = (int*)  alloc((size_t)NBLK * 4);
    int*   boff      = (int*)  alloc((size_t)NBLK * 4);
    unsigned short* h2 = (unsigned short*)alloc((size_t)N_NODES * ODIM2 * 2);
    unsigned short* Wp = (unsigned short*)alloc((size_t)65536 * 2);

    hipMemsetAsync(cnt, 0, N_NODES * sizeof(int), stream);

    k_count     <<<(NEDGE + 255) / 256, 256, 0, stream>>>(ei, cnt);
    k_blocksum  <<<NBLK,                256, 0, stream>>>(cnt, bsum);
    k_scanblocks<<<1,                   256, 0, stream>>>(bsum, boff);
    k_apply     <<<NBLK,                256, 0, stream>>>(cnt, boff, row_start, pos, dinv);
    k_fill      <<<(NEDGE + 255) / 256, 256, 0, stream>>>(ei, pos, csr);
    k_wconv     <<<32,                  256, 0, stream>>>(Wmu, Wls, Wp);
    k_gemm_mfma <<<(N_NODES + 63) / 64, 256, 0, stream>>>(x, Wp, h2);
    k_gather_s  <<<(N_NODES / 4) * 8,   256, 0, stream>>>(row_start, csr, dinv, h2,
                                                          eps, bmu, bls, z);
}

// Round 8
// 208.927 us; speedup vs baseline: 1.9008x; 1.9008x over previous
//
#include <hip/hip_runtime.h>
#include <hip/hip_bf16.h>

#define N_NODES 50000
#define IN_DIM 256
#define OUT_DIM 128
#define ODIM2 256        // mu(128) + logstd(128) concatenated
#define NEDGE 800000
#define MAX_LOGSTD 10.0f
#define NBLK 196         // ceil(50000/256)

typedef short bf16x8 __attribute__((ext_vector_type(8)));
typedef float f32x4  __attribute__((ext_vector_type(4)));

__device__ __forceinline__ float b2f(unsigned short u) {
    union { unsigned int i; float f; } v; v.i = ((unsigned int)u) << 16; return v.f;
}
__device__ __forceinline__ unsigned short f2b(float f) {
    union { float f; unsigned int i; } v; v.f = f;
    unsigned int x = v.i;
    unsigned int r = (x + 0x7fffu + ((x >> 16) & 1u)) >> 16;
    return (unsigned short)r;
}
__device__ __forceinline__ bool edges_are_i64(const int* raw) {
    bool is64 = true;
    #pragma unroll
    for (int i = 0; i < 8; i++) if (raw[2 * i + 1] != 0) is64 = false;
    return is64;
}

// dst histogram straight from raw edge buffer (int64 or int32 auto-detected)
__global__ void k_count(const int* __restrict__ raw, int* __restrict__ cnt) {
    bool is64 = edges_are_i64(raw);
    int e = blockIdx.x * blockDim.x + threadIdx.x;
    if (e < NEDGE) {
        int dst = is64 ? raw[2 * (NEDGE + e)] : raw[NEDGE + e];
        atomicAdd(&cnt[dst], 1);
    }
}

// Phase 1: per-block (256 counts) sums
__global__ __launch_bounds__(256) void k_blocksum(const int* __restrict__ cnt,
                                                  int* __restrict__ bsum) {
    int idx = blockIdx.x * 256 + threadIdx.x;
    int v = (idx < N_NODES) ? cnt[idx] : 0;
    #pragma unroll
    for (int o = 32; o > 0; o >>= 1) v += __shfl_down(v, o);
    __shared__ int wsum[4];
    int lane = threadIdx.x & 63, w = threadIdx.x >> 6;
    if (lane == 0) wsum[w] = v;
    __syncthreads();
    if (threadIdx.x == 0) bsum[blockIdx.x] = wsum[0] + wsum[1] + wsum[2] + wsum[3];
}

// Phase 2: scan 196 block sums -> exclusive block offsets
__global__ __launch_bounds__(256) void k_scanblocks(const int* __restrict__ bsum,
                                                    int* __restrict__ boff) {
    __shared__ int s[256];
    int t = threadIdx.x;
    s[t] = (t < NBLK) ? bsum[t] : 0;
    __syncthreads();
    for (int o = 1; o < 256; o <<= 1) {
        int v = (t >= o) ? s[t - o] : 0;
        __syncthreads();
        s[t] += v;
        __syncthreads();
    }
    if (t < NBLK) boff[t] = (t == 0) ? 0 : s[t - 1];
}

// Phase 3: in-block exclusive scan + offset -> row_start, pos; dinv fused.
__global__ __launch_bounds__(256) void k_apply(const int* __restrict__ cnt,
                                               const int* __restrict__ boff,
                                               int* __restrict__ row_start,
                                               int* __restrict__ pos,
                                               float* __restrict__ dinv) {
    __shared__ int s[256];
    int t = threadIdx.x;
    int idx = blockIdx.x * 256 + t;
    int c = (idx < N_NODES) ? cnt[idx] : 0;
    s[t] = c;
    __syncthreads();
    for (int o = 1; o < 256; o <<= 1) {
        int v = (t >= o) ? s[t - o] : 0;
        __syncthreads();
        s[t] += v;
        __syncthreads();
    }
    int excl = boff[blockIdx.x] + s[t] - c;
    if (idx < N_NODES) {
        row_start[idx] = excl;
        pos[idx] = excl;
        dinv[idx] = rsqrtf((float)c + 1.0f);
    }
    if (idx == N_NODES - 1) row_start[N_NODES] = NEDGE;
}

// Bin edges by dst directly from raw: csr[row_start[dst]+k] = src
__global__ void k_fill(const int* __restrict__ raw, int* __restrict__ pos,
                       int* __restrict__ csr) {
    bool is64 = edges_are_i64(raw);
    int e = blockIdx.x * blockDim.x + threadIdx.x;
    if (e < NEDGE) {
        int src = is64 ? raw[2 * e] : raw[e];
        int dst = is64 ? raw[2 * (NEDGE + e)] : raw[NEDGE + e];
        int p = atomicAdd(&pos[dst], 1);
        csr[p] = src;
    }
}

// Pack concat(Wmu,Wls) [256 x 256] f32 into B-fragment-ordered bf16:
// Wp[((tile*8 + kk)*64 + lane)*8 + j] = W[kk*32 + (lane>>4)*8 + j][tile*16 + (lane&15)]
__global__ void k_wconv(const float* __restrict__ Wmu, const float* __restrict__ Wls,
                        unsigned short* __restrict__ Wp) {
    int i = blockIdx.x * blockDim.x + threadIdx.x;   // 8192 threads
    int lane = i & 63;
    int kk   = (i >> 6) & 7;
    int tile = i >> 9;
    int k0 = kk * 32 + (lane >> 4) * 8;
    int n  = tile * 16 + (lane & 15);
    const float* W = (n < 128) ? (Wmu + n) : (Wls + (n - 128));
    unsigned short o[8];
    #pragma unroll
    for (int j = 0; j < 8; j++) o[j] = f2b(W[(size_t)(k0 + j) * OUT_DIM]);
    ushort4 lo = { o[0], o[1], o[2], o[3] };
    ushort4 hi = { o[4], o[5], o[6], o[7] };
    *(ushort4*)(Wp + (size_t)i * 8)     = lo;
    *(ushort4*)(Wp + (size_t)i * 8 + 4) = hi;
}

// MFMA GEMM -> hs (PRE-SCALED): hs[n][c] = dinv[n] * (x@W)[n][c]  (bf16, flat)
__global__ __launch_bounds__(256, 2) void k_gemm_mfma(
    const float* __restrict__ x, const unsigned short* __restrict__ Wp,
    const float* __restrict__ dinv, unsigned short* __restrict__ hs)
{
    __shared__ unsigned short xs[64 * 256];   // 32 KB, swizzled
    const int tid  = threadIdx.x;
    const int lane = tid & 63;
    const int w    = tid >> 6;
    const int row0 = blockIdx.x * 64;

    // B fragments for this wave's 4 col-tiles, all 8 k-steps: loaded ONCE.
    bf16x8 breg[4][8];
    #pragma unroll
    for (int t = 0; t < 4; t++)
        #pragma unroll
        for (int kk = 0; kk < 8; kk++)
            breg[t][kk] = ((const bf16x8*)Wp)[((4 * w + t) * 8 + kk) * 64 + lane];

    // stage 64x256 f32 -> bf16 (XOR-swizzled rows)
    #pragma unroll
    for (int i = 0; i < 16; i++) {
        int f   = i * 256 + tid;
        int row = f >> 6;
        int c4  = f & 63;
        int grow = row0 + row;
        float4 v = make_float4(0.f, 0.f, 0.f, 0.f);
        if (grow < N_NODES) v = *(const float4*)(x + (size_t)grow * IN_DIM + c4 * 4);
        ushort4 b = { f2b(v.x), f2b(v.y), f2b(v.z), f2b(v.w) };
        unsigned int byte = (unsigned)(row * 512 + c4 * 8);
        byte ^= (unsigned)((row & 7) << 4);
        *(ushort4*)((char*)xs + byte) = b;
    }
    __syncthreads();

    #pragma unroll
    for (int sub = 0; sub < 4; sub++) {
        const int arow = sub * 16 + (lane & 15);
        const unsigned int abase = (unsigned)(arow * 512 + (lane >> 4) * 16);
        const unsigned int axor  = (unsigned)((arow & 7) << 4);

        bf16x8 a[8];
        #pragma unroll
        for (int kk = 0; kk < 8; kk++)
            a[kk] = *(const bf16x8*)((const char*)xs + ((abase + kk * 64) ^ axor));

        f32x4 acc[4];
        #pragma unroll
        for (int t = 0; t < 4; t++) acc[t] = (f32x4){0.f, 0.f, 0.f, 0.f};

        #pragma unroll
        for (int kk = 0; kk < 8; kk++)
            #pragma unroll
            for (int t = 0; t < 4; t++)
                acc[t] = __builtin_amdgcn_mfma_f32_16x16x32_bf16(a[kk], breg[t][kk],
                                                                 acc[t], 0, 0, 0);

        // C/D layout: col=lane&15, row=(lane>>4)*4+reg; scale by dinv[row] on store
        const int rbase = row0 + sub * 16 + (lane >> 4) * 4;
        const int cl = lane & 15;
        float dv[4];
        #pragma unroll
        for (int r = 0; r < 4; r++)
            dv[r] = (rbase + r < N_NODES) ? dinv[rbase + r] : 0.0f;
        #pragma unroll
        for (int t = 0; t < 4; t++) {
            int col = (4 * w + t) * 16 + cl;
            #pragma unroll
            for (int r = 0; r < 4; r++) {
                int row = rbase + r;
                if (row < N_NODES)
                    hs[(size_t)row * ODIM2 + col] = f2b(acc[t][r] * dv[r]);
            }
        }
    }
}

// Wave-per-node pull gather over PRE-SCALED hs: pure accumulate (no per-edge
// dinv, no coef FMA). out = dinv_d * (sum_{s in N(d)} hs[s] + hs[d]).
// Lane l holds cols l*4..l*4+3 (l<32: mu, l>=32: logstd).
__global__ __launch_bounds__(256) void k_gather(
    const int* __restrict__ row_start, const int* __restrict__ csr,
    const float* __restrict__ dinv, const unsigned short* __restrict__ hs,
    const float* __restrict__ eps, const float* __restrict__ bmu,
    const float* __restrict__ bls, float* __restrict__ z)
{
    const int tid  = threadIdx.x;
    const int n    = blockIdx.x * 4 + (tid >> 6);
    const int lane = tid & 63;
    const float dn = dinv[n];

    float a0, a1, a2, a3;
    {   // self-loop seed: hs[n] (will be scaled by dn at the end)
        ushort4 v = ((const ushort4*)(hs + (size_t)n * ODIM2))[lane];
        a0 = b2f(v.x); a1 = b2f(v.y); a2 = b2f(v.z); a3 = b2f(v.w);
    }

    const int beg = row_start[n];
    const int end = row_start[n + 1];
    int j = beg;
    // head: advance to 4-aligned j so int4 csr loads are aligned
    for (; j < end && (j & 3); j++) {
        int s = csr[j];
        ushort4 v = ((const ushort4*)(hs + (size_t)s * ODIM2))[lane];
        a0 += b2f(v.x); a1 += b2f(v.y); a2 += b2f(v.z); a3 += b2f(v.w);
    }
    // main: 8 edges in flight, 2 aligned int4 index loads
    for (; j + 8 <= end; j += 8) {
        int4 sA = *(const int4*)(csr + j);
        int4 sB = *(const int4*)(csr + j + 4);
        ushort4 v0 = ((const ushort4*)(hs + (size_t)sA.x * ODIM2))[lane];
        ushort4 v1 = ((const ushort4*)(hs + (size_t)sA.y * ODIM2))[lane];
        ushort4 v2 = ((const ushort4*)(hs + (size_t)sA.z * ODIM2))[lane];
        ushort4 v3 = ((const ushort4*)(hs + (size_t)sA.w * ODIM2))[lane];
        ushort4 v4 = ((const ushort4*)(hs + (size_t)sB.x * ODIM2))[lane];
        ushort4 v5 = ((const ushort4*)(hs + (size_t)sB.y * ODIM2))[lane];
        ushort4 v6 = ((const ushort4*)(hs + (size_t)sB.z * ODIM2))[lane];
        ushort4 v7 = ((const ushort4*)(hs + (size_t)sB.w * ODIM2))[lane];
        a0 += b2f(v0.x); a1 += b2f(v0.y); a2 += b2f(v0.z); a3 += b2f(v0.w);
        a0 += b2f(v1.x); a1 += b2f(v1.y); a2 += b2f(v1.z); a3 += b2f(v1.w);
        a0 += b2f(v2.x); a1 += b2f(v2.y); a2 += b2f(v2.z); a3 += b2f(v2.w);
        a0 += b2f(v3.x); a1 += b2f(v3.y); a2 += b2f(v3.z); a3 += b2f(v3.w);
        a0 += b2f(v4.x); a1 += b2f(v4.y); a2 += b2f(v4.z); a3 += b2f(v4.w);
        a0 += b2f(v5.x); a1 += b2f(v5.y); a2 += b2f(v5.z); a3 += b2f(v5.w);
        a0 += b2f(v6.x); a1 += b2f(v6.y); a2 += b2f(v6.z); a3 += b2f(v6.w);
        a0 += b2f(v7.x); a1 += b2f(v7.y); a2 += b2f(v7.z); a3 += b2f(v7.w);
    }
    // tail: 4 then singles
    if (j + 4 <= end) {
        int4 sA = *(const int4*)(csr + j);
        ushort4 v0 = ((const ushort4*)(hs + (size_t)sA.x * ODIM2))[lane];
        ushort4 v1 = ((const ushort4*)(hs + (size_t)sA.y * ODIM2))[lane];
        ushort4 v2 = ((const ushort4*)(hs + (size_t)sA.z * ODIM2))[lane];
        ushort4 v3 = ((const ushort4*)(hs + (size_t)sA.w * ODIM2))[lane];
        a0 += b2f(v0.x); a1 += b2f(v0.y); a2 += b2f(v0.z); a3 += b2f(v0.w);
        a0 += b2f(v1.x); a1 += b2f(v1.y); a2 += b2f(v1.z); a3 += b2f(v1.w);
        a0 += b2f(v2.x); a1 += b2f(v2.y); a2 += b2f(v2.z); a3 += b2f(v2.w);
        a0 += b2f(v3.x); a1 += b2f(v3.y); a2 += b2f(v3.z); a3 += b2f(v3.w);
        j += 4;
    }
    for (; j < end; j++) {
        int s = csr[j];
        ushort4 v = ((const ushort4*)(hs + (size_t)s * ODIM2))[lane];
        a0 += b2f(v.x); a1 += b2f(v.y); a2 += b2f(v.z); a3 += b2f(v.w);
    }

    // bring logstd (lanes 32..63) to the matching mu lane
    float l0 = __shfl(a0, lane | 32);
    float l1 = __shfl(a1, lane | 32);
    float l2 = __shfl(a2, lane | 32);
    float l3 = __shfl(a3, lane | 32);

    if (lane < 32) {
        int c = lane * 4;
        float4 ep = *(const float4*)(eps + (size_t)n * OUT_DIM + c);
        float4 bm = *(const float4*)(bmu + c);
        float4 bl = *(const float4*)(bls + c);
        float4 o;
        o.x = dn * a0 + bm.x + ep.x * expf(fminf(dn * l0 + bl.x, MAX_LOGSTD));
        o.y = dn * a1 + bm.y + ep.y * expf(fminf(dn * l1 + bl.y, MAX_LOGSTD));
        o.z = dn * a2 + bm.z + ep.z * expf(fminf(dn * l2 + bl.z, MAX_LOGSTD));
        o.w = dn * a3 + bm.w + ep.w * expf(fminf(dn * l3 + bl.w, MAX_LOGSTD));
        *(float4*)(z + (size_t)n * OUT_DIM + c) = o;
    }
}

extern "C" void kernel_launch(void* const* d_in, const int* in_sizes, int n_in,
                              void* d_out, int out_size, void* d_ws, size_t ws_size,
                              hipStream_t stream) {
    const float* x   = (const float*)d_in[0];
    const int*   ei  = (const int*)  d_in[1];
    const float* Wmu = (const float*)d_in[2];
    const float* bmu = (const float*)d_in[3];
    const float* Wls = (const float*)d_in[4];
    const float* bls = (const float*)d_in[5];
    const float* eps = (const float*)d_in[6];
    float* z = (float*)d_out;

    char* ws = (char*)d_ws;
    size_t off = 0;
    auto alloc = [&](size_t bytes) {
        void* p = ws + off;
        off += (bytes + 255) & ~(size_t)255;
        return p;
    };
    int*   cnt       = (int*)  alloc((size_t)N_NODES * 4);
    float* dinv      = (float*)alloc((size_t)N_NODES * 4);
    int*   row_start = (int*)  alloc((size_t)(N_NODES + 1) * 4);
    int*   pos       = (int*)  alloc((size_t)N_NODES * 4);
    int*   csr       = (int*)  alloc((size_t)NEDGE * 4);
    int*   bsum      = (int*)  alloc((size_t)NBLK * 4);
    int*   boff      = (int*)  alloc((size_t)NBLK * 4);
    unsigned short* hs = (unsigned short*)alloc((size_t)N_NODES * ODIM2 * 2);
    unsigned short* Wp = (unsigned short*)alloc((size_t)65536 * 2);

    hipMemsetAsync(cnt, 0, N_NODES * sizeof(int), stream);

    k_count     <<<(NEDGE + 255) / 256, 256, 0, stream>>>(ei, cnt);
    k_blocksum  <<<NBLK,                256, 0, stream>>>(cnt, bsum);
    k_scanblocks<<<1,                   256, 0, stream>>>(bsum, boff);
    k_apply     <<<NBLK,                256, 0, stream>>>(cnt, boff, row_start, pos, dinv);
    k_fill      <<<(NEDGE + 255) / 256, 256, 0, stream>>>(ei, pos, csr);
    k_wconv     <<<32,                  256, 0, stream>>>(Wmu, Wls, Wp);
    k_gemm_mfma <<<(N_NODES + 63) / 64, 256, 0, stream>>>(x, Wp, dinv, hs);
    k_gather    <<<N_NODES / 4,         256, 0, stream>>>(row_start, csr, dinv, hs,
                                                          eps, bmu, bls, z);
}